// Round 4
// baseline (205.319 us; speedup 1.0000x reference)
//
#include <hip/hip_runtime.h>
#include <math.h>

// CalWeight: out[b,j] = phi[b,j] - phi[b,(j+1)%N]
//   phi[b,j] = atan2(verts_y[b,j] - row[b], verts_x[b,j] - col[b])
// x layout per row: [col, row, v0x, v0y, ..., v1023x, v1023y], stride 2050 f32.
//
// OCML atan2f uses the precise-division chain + special-case handling
// (~60-100 VALU ops) -> kernel was VALU-bound at 204 us vs ~32 us HBM floor.
// Pass threshold is 0.1256 ABSOLUTE, so a minimax poly atan (max err
// ~2.4e-5 rad) + v_rcp_f32 (~1 ulp) is 4 orders of magnitude inside
// tolerance at ~20 VALU ops.

#define NVERT 1024
#define ROWSTRIDE (2 + 2 * NVERT)
#define BLK 256

__device__ __forceinline__ float fast_atan2f(float y, float x) {
    const float a = __builtin_fabsf(y);
    const float b = __builtin_fabsf(x);
    const float mn = fminf(a, b);
    const float mx = fmaxf(a, b);
    // t = mn/mx via hardware v_rcp_f32 (~1 ulp). Guard mx==0/denormal -> t=0
    // (atan2(0,0)=0 matches numpy; denormal diffs are measure-zero anyway).
    float t = (mx > 1.17549435e-38f) ? mn * __builtin_amdgcn_rcpf(mx) : 0.0f;
    // minimax odd poly for atan on [0,1], max abs err ~2.4e-5 rad
    const float s = t * t;
    float p = -1.1721200e-02f;
    p = fmaf(p, s, 5.2653320e-02f);
    p = fmaf(p, s, -1.1643287e-01f);
    p = fmaf(p, s, 1.9354346e-01f);
    p = fmaf(p, s, -3.3262347e-01f);
    p = fmaf(p, s, 9.9997726e-01f);
    float r = t * p;
    // quadrant fixups (branchless -> v_cndmask)
    r = (a > b) ? (1.57079632679f - r) : r;   // |y| > |x|
    r = (x < 0.0f) ? (3.14159265359f - r) : r;
    return __builtin_copysignf(r, y);
}

__global__ __launch_bounds__(BLK) void calweight_kernel(const float* __restrict__ x,
                                                        float* __restrict__ out) {
    const int b = blockIdx.x;
    const int t = threadIdx.x;

    const float* __restrict__ xr = x + (size_t)b * ROWSTRIDE;
    const float colv = xr[0];
    const float rowv = xr[1];

    __shared__ float phi[NVERT];

    // Phase 1: coalesced float2 vertex loads (8B-aligned: (b*2050+2)*4 % 8 == 0).
    const float2* __restrict__ verts = (const float2*)(xr + 2);
#pragma unroll
    for (int k = 0; k < NVERT / BLK; ++k) {
        const int j = t + k * BLK;
        const float2 v = verts[j];
        phi[j] = fast_atan2f(v.y - rowv, v.x - colv);
    }
    __syncthreads();

    // Phase 2: 4 consecutive outputs per thread as one float4 store.
    float* __restrict__ orow = out + (size_t)b * NVERT;
    const int j0 = 4 * t;
    const float4 p = ((const float4*)phi)[t];
    const float pn = phi[(j0 + 4) & (NVERT - 1)];  // wrap: j=1023 -> phi[0]
    float4 r;
    r.x = p.x - p.y;
    r.y = p.y - p.z;
    r.z = p.z - p.w;
    r.w = p.w - pn;
    ((float4*)orow)[t] = r;
}

extern "C" void kernel_launch(void* const* d_in, const int* in_sizes, int n_in,
                              void* d_out, int out_size, void* d_ws, size_t ws_size,
                              hipStream_t stream) {
    const float* x = (const float*)d_in[0];
    float* out = (float*)d_out;
    const int B = in_sizes[0] / ROWSTRIDE;  // 16384
    calweight_kernel<<<B, BLK, 0, stream>>>(x, out);
}